// Round 13
// baseline (1848.586 us; speedup 1.0000x reference)
//
#include <hip/hip_runtime.h>
#include <hip/hip_bf16.h>
#include <cstdint>

#define NTOK 8192
#define NEXP 8
#define HID  2048
#define INTR 5632
#define NT1  44     // INTR/128 n-tiles for gemm1
#define NT2  16     // HID/128  n-tiles for gemm2

// ws offsets (bytes)
#define TCNT_OFF    4096u
#define SLOT_OFF    65536u      // slotlist: 18432 ints
#define T2S_OFF     262144u     // tok2slot: 32768 ints
#define W2_OFF      393216u     // w2: 32768 floats
#define LISTS_OFF   524288u     // lists: 65536 ints
#define WL_OFF      786432u     // wlists: 65536 floats
#define WG_OFF      2097152u
#define WBYTES      184549376u
#define WU_OFF      (WG_OFF + WBYTES)
#define HF_OFF      (WU_OFF + WBYTES)
#define HFBYTES     207618048u  // 72 mtiles * 176 kt * 16 frags * 1024 B
#define XG_OFF      (HF_OFF + HFBYTES)   // xg (75.5MB) then reused as pout

typedef float f32x4  __attribute__((ext_vector_type(4)));
typedef short s16x8  __attribute__((ext_vector_type(8)));
typedef short s16x4  __attribute__((ext_vector_type(4)));

__device__ __forceinline__ short bfc(float f) {
  __hip_bfloat16 h = __float2bfloat16(f);
  return __builtin_bit_cast(short, h);
}
__device__ __forceinline__ float b2f(short s) {
  unsigned u = ((unsigned)(unsigned short)s) << 16;
  return __builtin_bit_cast(float, u);
}
__device__ __forceinline__ s16x8 pk8(float4 a, float4 b) {
  s16x8 v;
  v[0]=bfc(a.x); v[1]=bfc(a.y); v[2]=bfc(a.z); v[3]=bfc(a.w);
  v[4]=bfc(b.x); v[5]=bfc(b.y); v[6]=bfc(b.z); v[7]=bfc(b.w);
  return v;
}
__device__ __forceinline__ void gload16(const void* g, void* l) {
  __builtin_amdgcn_global_load_lds((const __attribute__((address_space(1))) void*)g,
                                   (__attribute__((address_space(3))) void*)l, 16, 0, 0);
}

#define DSR128(dst, addr, IMM) \
  asm volatile("ds_read_b128 %0, %1 offset:" IMM : "=v"(dst) : "v"(addr))
#define WAITLGKM(N) do { \
  asm volatile("s_waitcnt lgkmcnt(" #N ")" ::: "memory"); \
  __builtin_amdgcn_sched_barrier(0); } while (0)
#define WAITVM(N) do { \
  asm volatile("s_waitcnt vmcnt(" #N ")" ::: "memory"); \
  __builtin_amdgcn_sched_barrier(0); } while (0)

#define MFMA_BF16 __builtin_amdgcn_mfma_f32_16x16x32_bf16

// ---------------- prep: f32 weights -> bf16 MFMA B-fragment layout ----------------
__global__ __launch_bounds__(256, 4) void prep_kernel(
    const float* __restrict__ src, short* __restrict__ dst,
    int KT, int NP, int Nsrc) {
  __shared__ float tile[32 * 132];
  const int b = blockIdx.x;
  const int np = b % NP;
  const int kt = (b / NP) % KT;
  const int e  = b / (NP * KT);
  const int tid = threadIdx.x;
  const float* s = src + (size_t)e * KT * 32 * (size_t)Nsrc + (size_t)kt * 32 * Nsrc + np * 128;
#pragma unroll
  for (int i = 0; i < 4; i++) {
    const int idx = tid + i * 256;
    const int row = idx >> 5, c4 = idx & 31;
    float4 v = *(const float4*)(s + (size_t)row * Nsrc + c4 * 4);
    *(float4*)(tile + row * 132 + c4 * 4) = v;
  }
  __syncthreads();
  short* dbase = dst + ((size_t)(e * KT + kt) * (NP * 8) + np * 8) * 512;
#pragma unroll
  for (int i = 0; i < 2; i++) {
    const int c = tid + i * 256;
    const int lane = c & 63;
    const int nf = c >> 6;
    const int n = nf * 16 + (lane & 15);
    const int kb = (lane >> 4) * 8;
    s16x8 o;
#pragma unroll
    for (int j = 0; j < 8; j++) o[j] = bfc(tile[(kb + j) * 132 + n]);
    *(s16x8*)(dbase + (size_t)c * 8) = o;
  }
}

// ---------------- router ----------------
__global__ void router_kernel(const float* __restrict__ x, const float* __restrict__ wr,
                              int* __restrict__ cnt, int* __restrict__ lists,
                              float* __restrict__ wlists) {
  const int wave = threadIdx.x >> 6;
  const int lane = threadIdx.x & 63;
  const int t = blockIdx.x * 4 + wave;
  if (t >= NTOK) return;
  float acc[NEXP];
#pragma unroll
  for (int e = 0; e < NEXP; e++) acc[e] = 0.f;
  const float* xrow = x + (size_t)t * HID;
#pragma unroll
  for (int j = 0; j < HID / 256; j++) {
    const int k = j * 256 + lane * 4;
    float4 xv = *(const float4*)(xrow + k);
#pragma unroll
    for (int e = 0; e < NEXP; e++) {
      float4 wv = *(const float4*)(wr + e * HID + k);
      acc[e] += xv.x * wv.x + xv.y * wv.y + xv.z * wv.z + xv.w * wv.w;
    }
  }
#pragma unroll
  for (int e = 0; e < NEXP; e++) {
    float v = acc[e];
    for (int off = 32; off; off >>= 1) v += __shfl_xor(v, off, 64);
    acc[e] = v;
  }
  if (lane == 0) {
    float m = acc[0];
#pragma unroll
    for (int e = 1; e < NEXP; e++) m = fmaxf(m, acc[e]);
    float p[NEXP], s = 0.f;
#pragma unroll
    for (int e = 0; e < NEXP; e++) { p[e] = __expf(acc[e] - m); s += p[e]; }
    const float inv = 1.f / s;
    int e1 = 0; float b1 = p[0];
#pragma unroll
    for (int e = 1; e < NEXP; e++) if (p[e] > b1) { b1 = p[e]; e1 = e; }
    int e2 = -1; float b2 = -1.f;
#pragma unroll
    for (int e = 0; e < NEXP; e++) if (e != e1 && p[e] > b2) { b2 = p[e]; e2 = e; }
    const int pos1 = atomicAdd(&cnt[e1], 1);
    lists[e1 * NTOK + pos1] = t; wlists[e1 * NTOK + pos1] = b1 * inv;
    const int pos2 = atomicAdd(&cnt[e2], 1);
    lists[e2 * NTOK + pos2] = t; wlists[e2 * NTOK + pos2] = b2 * inv;
  }
}

__global__ void offsets_kernel(const int* __restrict__ cnt, int* __restrict__ poffs) {
  if (threadIdx.x == 0 && blockIdx.x == 0) {
    int o = 0;
#pragma unroll
    for (int e = 0; e < NEXP; e++) { poffs[e] = o; o += ((cnt[e] + 255) >> 8) << 8; }
    poffs[NEXP] = o;
  }
}

// ---------------- slotmap ----------------
__global__ void slotmap_kernel(const int* __restrict__ cnt, const int* __restrict__ poffs,
                               const int* __restrict__ lists, const float* __restrict__ wlists,
                               int* __restrict__ slotlist, int* __restrict__ tcnt,
                               int* __restrict__ tok2slot, float* __restrict__ w2) {
  const int e = blockIdx.x;
  const int c = cnt[e], base = poffs[e];
  for (int pos = threadIdx.x; pos < c; pos += blockDim.x) {
    const int tok = lists[e * NTOK + pos];
    const int slot = base + pos;
    slotlist[slot] = tok;
    const int j = atomicAdd(&tcnt[tok], 1);
    tok2slot[tok * 2 + j] = slot;
    w2[tok * 2 + j] = wlists[e * NTOK + pos];
  }
}

// ---------------- gather: x (f32) -> xg bf16 in A-fragment layout ----------------
__global__ __launch_bounds__(256, 4) void gather_kernel(
    const float* __restrict__ x, const int* __restrict__ slotlist,
    short* __restrict__ xg) {
  const int c = blockIdx.x * 256 + threadIdx.x;
  const int cl = c & 63;
  const int fragid = c >> 6;
  const int f = fragid & 15;
  const int kt = (fragid >> 4) & 63;
  const int gmt = fragid >> 10;
  const int tok = slotlist[gmt * 256 + f * 16 + (cl & 15)];
  const float* s = x + (size_t)tok * HID + kt * 32 + (cl >> 4) * 8;
  float4 a = *(const float4*)s, b = *(const float4*)(s + 4);
  *(s16x8*)(xg + (size_t)c * 8) = pk8(a, b);
}

// ---------------- gemm1: m201-style 4-phase schedule ----------------
// Tile 256 x [128 gate | 128 up] (B = wgb++wub panels), 8 waves 2Mx4N,
// wave tile 128x64 (acc 8x4 = 128 AGPR), BK=64, 2 x 64KB LDS buffers.
// Per iter 4 phases (q=m-half, ks): {8 ds_read, 2 gload16 stage, counted
// WAITVM(4) in P1/P3 only, barrier, lgkm(0), 16 MFMA w/ setprio, barrier}.
__global__ __launch_bounds__(512, 2) void gemm1_kernel(
    const short* __restrict__ xg, const short* __restrict__ wgb,
    const short* __restrict__ wub, const int* __restrict__ cnt,
    const int* __restrict__ poffs, short* __restrict__ hfrag) {
  const int P = blockIdx.x;
  const int xcd = P & 7, slot = P >> 3;
  const int mt = slot & 31, jj = slot >> 5;
  const int g = jj * 8 + xcd;                 // (e,nt) group pinned to xcd
  const int e = g / NT1, nt = g % NT1;
  if (mt * 256 >= cnt[e]) return;
  const int gmt = (poffs[e] >> 8) + mt;
  const int tid = threadIdx.x;
  const int w = tid >> 6, lane = tid & 63;
  const int wm = w >> 2, wn = w & 3;          // 2M x 4N

  // 2 buffers x 32768 shorts: [A ks0 8192][A ks1 8192][B ks0: Bg 4096|Bu 4096][B ks1: ...]
  __shared__ __align__(16) short Lds[65536];  // 131072 B
  short* LdsS = (short*)Lds;
  const uint32_t ldsbase = (uint32_t)(uintptr_t)&Lds[0];

  const short* pAs = xg + (size_t)gmt * 524288 + tid * 8;
  const short* pGs = wgb + (((size_t)e * 64) * 352 + nt * 8) * 512 + tid * 8;
  const short* pUs = wub + (((size_t)e * 64) * 352 + nt * 8) * 512 + tid * 8;

  const uint32_t ldsA = ldsbase + wm * 8192 + lane * 16;
  const uint32_t ldsB = ldsbase + 32768 + (wn >> 1) * 8192 + (wn & 1) * 4096 + lane * 16;

  f32x4 acc[8][4];
#pragma unroll
  for (int i = 0; i < 8; i++)
#pragma unroll
    for (int j = 0; j < 4; j++) acc[i][j] = f32x4{0.f, 0.f, 0.f, 0.f};

#define STG_A0() do { short* d = LdsS + WS;                                     \
    gload16(pAs,        d + tid * 8);                                           \
    gload16(pAs + 4096, d + 4096 + tid * 8); } while (0)
#define STG_B0() do { short* d = LdsS + WS;                                     \
    gload16(pGs, d + 16384 + tid * 8);                                          \
    gload16(pUs, d + 20480 + tid * 8); } while (0)
#define STG_A1() do { short* d = LdsS + WS;                                     \
    gload16(pAs + 8192,  d + 8192 + tid * 8);                                   \
    gload16(pAs + 12288, d + 12288 + tid * 8); } while (0)
#define STG_B1() do { short* d = LdsS + WS;                                     \
    gload16(pGs + 180224, d + 24576 + tid * 8);                                 \
    gload16(pUs + 180224, d + 28672 + tid * 8); } while (0)
#define ADV() do { pAs += 16384; pGs += 360448; pUs += 360448; } while (0)

#define PHASE1(KS, Q, VMSTMT, STGSTMT)                                          \
  {                                                                             \
    const uint32_t ra  = ldsA + RB + (KS) * 16384 + (Q) * 4096;                 \
    const uint32_t rbx = ldsB + RB + (KS) * 16384;                              \
    s16x8 av0, av1, av2, av3, bv0, bv1, bv2, bv3;                               \
    DSR128(av0, ra, "0");     DSR128(av1, ra, "1024");                          \
    DSR128(av2, ra, "2048");  DSR128(av3, ra, "3072");                          \
    DSR128(bv0, rbx, "0");    DSR128(bv1, rbx, "1024");                         \
    DSR128(bv2, rbx, "2048"); DSR128(bv3, rbx, "3072");                         \
    STGSTMT;                                                                    \
    VMSTMT;                                                                     \
    __builtin_amdgcn_s_barrier();                                               \
    WAITLGKM(0);                                                                \
    __builtin_amdgcn_s_setprio(1);                                              \
    acc[(Q)*4+0][0] = MFMA_BF16(av0, bv0, acc[(Q)*4+0][0], 0, 0, 0);            \
    acc[(Q)*4+0][1] = MFMA_BF16(av0, bv1, acc[(Q)*4+0][1], 0, 0, 0);            \
    acc[(Q)*4+0][2] = MFMA_BF16(av0, bv2, acc[(Q)*4+0][2], 0, 0, 0);            \
    acc[(Q)*4+0][3] = MFMA_BF16(av0, bv3, acc[(Q)*4+0][3], 0, 0, 0);            \
    acc[(Q)*4+1][0] = MFMA_BF16(av1, bv0, acc[(Q)*4+1][0], 0, 0, 0);            \
    acc[(Q)*4+1][1] = MFMA_BF16(av1, bv1, acc[(Q)*4+1][1], 0, 0, 0);            \
    acc[(Q)*4+1][2] = MFMA_BF16(av1, bv2, acc[(Q)*4+1][2], 0, 0, 0);            \
    acc[(Q)*4+1][3] = MFMA_BF16(av1, bv3, acc[(Q)*4+1][3], 0, 0, 0);            \
    acc[(Q)*4+2][0] = MFMA_BF16(av2, bv0, acc[(Q)*4+2][0], 0, 0, 0);            \
    acc[(Q)*4+2][1] = MFMA_BF16(av2, bv1, acc[(Q)*4+2][1], 0, 0, 0);            \
    acc[(Q)*4+2][2] = MFMA_BF16(av2, bv2, acc[(Q)*4+2][2], 0, 0, 0);            \
    acc[(Q)*4+2][3] = MFMA_BF16(av2, bv3, acc[(Q)*4+2][3], 0, 0, 0);            \
    acc[(Q)*4+3][0] = MFMA_BF16(av3, bv0, acc[(Q)*4+3][0], 0, 0, 0);            \
    acc[(Q)*4+3][1] = MFMA_BF16(av3, bv1, acc[(Q)*4+3][1], 0, 0, 0);            \
    acc[(Q)*4+3][2] = MFMA_BF16(av3, bv2, acc[(Q)*4+3][2], 0, 0, 0);            \
    acc[(Q)*4+3][3] = MFMA_BF16(av3, bv3, acc[(Q)*4+3][3], 0, 0, 0);            \
    __builtin_amdgcn_s_setprio(0);                                              \
    __builtin_amdgcn_s_barrier();                                               \
  }

  // prologue: stage iter-0 buffer (buf0), H0 first then H1
  int WS = 0;
  STG_A0(); STG_B0(); STG_A1(); STG_B1(); ADV();
  WS = 32768;
  WAITVM(4);                        // H0(0) done; H1(0) in flight
  __builtin_amdgcn_s_barrier();

  uint32_t RB = 0;
  for (int t = 0; t < 31; ++t) {
    PHASE1(0, 0, (void)0,   STG_A0())
    PHASE1(0, 1, WAITVM(4), STG_B0())
    PHASE1(1, 0, (void)0,   STG_A1())
    PHASE1(1, 1, WAITVM(4), STG_B1(); ADV())
    RB ^= 65536; WS ^= 32768;
  }
  // t = 31: no staging
  PHASE1(0, 0, (void)0,   (void)0)
  PHASE1(0, 1, WAITVM(0), (void)0)
  PHASE1(1, 0, (void)0,   (void)0)
  PHASE1(1, 1, (void)0,   (void)0)
#undef PHASE1
#undef STG_A0
#undef STG_B0
#undef STG_A1
#undef STG_B1
#undef ADV

  // epilogue: G and U live in different waves -> stage both in swizzled LDS,
  // combine silu(G)*U on readback, store in gemm2 A-frag layout.
  short* trG = LdsS;            // 256x128 shorts (64KB), idx swizzled
  short* trU = LdsS + 32768;    // 256x128 shorts (64KB)
  __syncthreads();
#pragma unroll
  for (int mf = 0; mf < 8; mf++)
#pragma unroll
    for (int reg = 0; reg < 4; reg++) {
      const int row = wm * 128 + mf * 16 + (lane >> 4) * 4 + reg;
      short* dst = (wn < 2) ? trG : trU;
#pragma unroll
      for (int nf = 0; nf < 4; nf++) {
        const int col = (wn & 1) * 64 + nf * 16 + (lane & 15);
        dst[row * 128 + (col ^ ((row & 7) << 3))] = bfc(acc[mf][nf][reg]);
      }
    }
  __syncthreads();
  short* hb = hfrag + (((size_t)gmt * 176 + nt * 4) * 16) * 512;
#pragma unroll
  for (int i = 0; i < 8; i++) {
    const int c = tid + i * 512;             // 0..4095
    const int cl = c & 63;
    const int f = (c >> 6) & 15;
    const int ktl = c >> 10;                 // 0..3
    const int rr = f * 16 + (cl & 15);
    const int b = ktl * 32 + (cl >> 4) * 8;
    const int off = rr * 128 + (b ^ ((rr & 7) << 3));
    s16x8 gvv = *(const s16x8*)(trG + off);
    s16x8 uvv = *(const s16x8*)(trU + off);
    s16x8 o;
#pragma unroll
    for (int j = 0; j < 8; j++) {
      const float gv = b2f(gvv[j]);
      const float uv = b2f(uvv[j]);
      o[j] = bfc((gv / (1.f + __expf(-gv))) * uv);
    }
    *(s16x8*)(hb + ((size_t)ktl * 16 + f) * 512 + cl * 8) = o;
  }
}

// ---------------- gemm2: round-6 proven version (pure gload16, triple buffer) -----
__global__ __launch_bounds__(512, 4) void gemm2_kernel(
    const short* __restrict__ hfrag, const short* __restrict__ wdb,
    const int* __restrict__ cnt, const int* __restrict__ poffs,
    __hip_bfloat16* __restrict__ pout) {
  const int P = blockIdx.x;
  const int xcd = P & 7, r = P >> 3;
  const int nt = r & 15, emq = r >> 4;
  const int gm = emq * 8 + xcd;              // m-tile pinned to xcd
  const int e = gm >> 5, mt = gm & 31;
  if (mt * 256 >= cnt[e]) return;
  const int gmt = (poffs[e] >> 8) + mt;
  const int n0 = nt * 128;
  const int tid = threadIdx.x;
  const int w = tid >> 6, lane = tid & 63;
  const int wm = w >> 1, wn = w & 1;

  // per buffer (12288 shorts = 24KB): A 16 frags [0,8192), B 8 frags [8192,12288)
  __shared__ __align__(16) short Lds[3 * 12288];
  const uint32_t ldsbase = (uint32_t)(uintptr_t)&Lds[0];

  const short* srcA = hfrag + (size_t)gmt * 176 * 16 * 512 + tid * 8;
  const short* srcB = wdb + (((size_t)e * 176) * 128 + nt * 8) * 512 + tid * 8;

  const uint32_t roA = wm * 4096 + lane * 16;
  const uint32_t roB = 16384 + wn * 4096 + lane * 16;

  f32x4 acc[4][4];
#pragma unroll
  for (int i = 0; i < 4; i++)
#pragma unroll
    for (int j = 0; j < 4; j++) acc[i][j] = f32x4{0.f, 0.f, 0.f, 0.f};

#define STG2(WB) do {                                                           \
    short* d = (short*)Lds + ((WB) >> 1);                                       \
    gload16(srcA,        d + w * 512);                                          \
    gload16(srcA + 4096, d + 4096 + w * 512);                                   \
    gload16(srcB,        d + 8192 + w * 512);                                   \
    srcA += 8192; srcB += 65536; } while (0)

#define MMQ2(NF, BF)                                                            \
  { __builtin_amdgcn_s_setprio(1);                                              \
    acc[0][NF] = MFMA_BF16(af0, BF, acc[0][NF], 0, 0, 0);                       \
    acc[1][NF] = MFMA_BF16(af1, BF, acc[1][NF], 0, 0, 0);                       \
    acc[2][NF] = MFMA_BF16(af2, BF, acc[2][NF], 0, 0, 0);                       \
    acc[3][NF] = MFMA_BF16(af3, BF, acc[3][NF], 0, 0, 0);                       \
    __builtin_amdgcn_s_setprio(0); }

#define G2_BODY(RB, WB, VMN, DOSTG)                                             \
  {                                                                             \
    WAITVM(VMN);                                                                \
    __builtin_amdgcn_s_barrier();                                               \
    const uint32_t rb = ldsbase + (RB);                                         \
    s16x8 af0, af1, af2, af3, bf0, bf1, bf2, bf3;                               \
    DSR128(bf0, rb + roB, "0");                                                 \
    DSR128(af0, rb + roA, "0");    DSR128(af1, rb + roA, "1024");               \
    DSR128(af2, rb + roA, "2048"); DSR128(af3, rb + roA, "3072");               \
    DSR128(bf1, rb + roB, "1024");                                              \
    DSR128(bf2, rb + roB, "2048");                                              \
    DSR128(bf3, rb + roB, "3072");                                              \
    if (DOSTG) { STG2(WB); }                                                    \
    WAITLGKM(3);                                                                \
    MMQ2(0, bf0)                                                                \
    WAITLGKM(2);                                                                \
    MMQ2(1, bf1)                                                                \
    WAITLGKM(1);                                                                \
    MMQ2(2, bf2)                                                                \
    WAITLGKM(0);                                                                \
    MMQ2(3, bf3)                                                                \
  }

  STG2(0);
  STG2(24576);
  for (int it = 0; it < 58; ++it) {          // t = 0..173
    G2_BODY(0,     49152, 3, 1)
    G2_BODY(24576, 0,     3, 1)
    G2_BODY(49152, 24576, 3, 1)
  }
  G2_BODY(0,     0, 3, 0)                    // t=174
  G2_BODY(24576, 0, 0, 0)                    // t=175
#undef G2_BODY
#undef MMQ2
#undef STG2

  const int slotb = poffs[e] + mt * 256;
#pragma unroll
  for (int mf = 0; mf < 4; mf++) {
#pragma unroll
    for (int reg = 0; reg < 4; reg++) {
      const int row = wm * 64 + mf * 16 + (lane >> 4) * 4 + reg;
      __hip_bfloat16* op = pout + (size_t)(slotb + row) * HID + n0 + wn * 64 + (lane & 15);
#pragma unroll
      for (int nf = 0; nf < 4; nf++)
        op[nf * 16] = __float2bfloat16(acc[mf][nf][reg]);
    }
  }
}

// ---------------- combine ----------------
__global__ __launch_bounds__(256, 8) void combine_kernel(
    const __hip_bfloat16* __restrict__ pout, const int* __restrict__ tok2slot,
    const float* __restrict__ w2, float* __restrict__ out) {
  const int t = blockIdx.x;
  const int s0 = tok2slot[2 * t], s1 = tok2slot[2 * t + 1];
  const float w0 = w2[2 * t], w1 = w2[2 * t + 1];
  const short* p0 = (const short*)pout + (size_t)s0 * HID;
  const short* p1 = (const short*)pout + (size_t)s1 * HID;
  float* o = out + (size_t)t * HID;
  const int i = threadIdx.x;
  s16x8 a = *(const s16x8*)(p0 + i * 8);
  s16x8 b = *(const s16x8*)(p1 + i * 8);
  float4 r0, r1;
  r0.x = w0 * b2f(a[0]) + w1 * b2f(b[0]);
  r0.y = w0 * b2f(a[1]) + w1 * b2f(b[1]);
  r0.z = w0 * b2f(a[2]) + w1 * b2f(b[2]);
  r0.w = w0 * b2f(a[3]) + w1 * b2f(b[3]);
  r1.x = w0 * b2f(a[4]) + w1 * b2f(b[4]);
  r1.y = w0 * b2f(a[5]) + w1 * b2f(b[5]);
  r1.z = w0 * b2f(a[6]) + w1 * b2f(b[6]);
  r1.w = w0 * b2f(a[7]) + w1 * b2f(b[7]);
  *(float4*)(o + i * 8) = r0;
  *(float4*)(o + i * 8 + 4) = r1;
}

extern "C" void kernel_launch(void* const* d_in, const int* in_sizes, int n_in,
                              void* d_out, int out_size, void* d_ws, size_t ws_size,
                              hipStream_t stream) {
  const float* x  = (const float*)d_in[0];
  const float* wr = (const float*)d_in[1];
  const float* wg = (const float*)d_in[2];
  const float* wu = (const float*)d_in[3];
  const float* wd = (const float*)d_in[4];
  float* out = (float*)d_out;
  char* ws = (char*)d_ws;

  int* cnt      = (int*)ws;
  int* poffs    = (int*)(ws + 64);
  int* tcnt     = (int*)(ws + TCNT_OFF);
  int* slotlist = (int*)(ws + SLOT_OFF);
  int* tok2slot = (int*)(ws + T2S_OFF);
  float* w2     = (float*)(ws + W2_OFF);
  int* lists    = (int*)(ws + LISTS_OFF);
  float* wlists = (float*)(ws + WL_OFF);
  short* wgb    = (short*)(ws + WG_OFF);
  short* wub    = (short*)(ws + WU_OFF);
  short* wdb    = (short*)(ws + WG_OFF);     // reuses wgb region (after gemm1)
  short* hfrag  = (short*)(ws + HF_OFF);
  short* xg     = (short*)(ws + XG_OFF);
  __hip_bfloat16* pout = (__hip_bfloat16*)(ws + XG_OFF);  // reuses xg (after gemm1)

  (void)hipMemsetAsync(ws, 0, 256, stream);
  (void)hipMemsetAsync(ws + TCNT_OFF, 0, 32768, stream);
  (void)hipMemsetAsync(ws + SLOT_OFF, 0, 73728, stream);

  router_kernel<<<NTOK / 4, 256, 0, stream>>>(x, wr, cnt, lists, wlists);
  offsets_kernel<<<1, 64, 0, stream>>>(cnt, poffs);
  slotmap_kernel<<<NEXP, 256, 0, stream>>>(cnt, poffs, lists, wlists, slotlist, tcnt, tok2slot, w2);
  gather_kernel<<<18432, 256, 0, stream>>>(x, slotlist, xg);
  prep_kernel<<<NEXP * 64 * 44, 256, 0, stream>>>(wg, wgb, 64, 44, INTR);
  prep_kernel<<<NEXP * 64 * 44, 256, 0, stream>>>(wu, wub, 64, 44, INTR);
  gemm1_kernel<<<8 * 32 * NT1, 512, 0, stream>>>(xg, wgb, wub, cnt, poffs, hfrag);
  prep_kernel<<<NEXP * 176 * 16, 256, 0, stream>>>(wd, wdb, 176, 16, HID);
  gemm2_kernel<<<8 * 16 * 32, 512, 0, stream>>>(hfrag, wdb, cnt, poffs, pout);
  combine_kernel<<<NTOK, 256, 0, stream>>>(pout, tok2slot, w2, out);
}

// Round 14
// 1686.751 us; speedup vs baseline: 1.0959x; 1.0959x over previous
//
#include <hip/hip_runtime.h>
#include <hip/hip_bf16.h>
#include <cstdint>

#define NTOK 8192
#define NEXP 8
#define HID  2048
#define INTR 5632
#define NT1  44     // INTR/128 n-tiles for gemm1
#define NT2  16     // HID/128  n-tiles for gemm2

// ws offsets (bytes)
#define TCNT_OFF    4096u
#define SLOT_OFF    65536u      // slotlist: 18432 ints
#define T2S_OFF     262144u     // tok2slot: 32768 ints
#define W2_OFF      393216u     // w2: 32768 floats
#define LISTS_OFF   524288u     // lists: 65536 ints
#define WL_OFF      786432u     // wlists: 65536 floats
#define WG_OFF      2097152u
#define WBYTES      184549376u
#define WU_OFF      (WG_OFF + WBYTES)
#define HF_OFF      (WU_OFF + WBYTES)
#define HFBYTES     207618048u  // 72 mtiles * 176 kt * 16 frags * 1024 B
#define XG_OFF      (HF_OFF + HFBYTES)   // xg (75.5MB) then reused as pout

typedef float f32x4  __attribute__((ext_vector_type(4)));
typedef short s16x8  __attribute__((ext_vector_type(8)));
typedef short s16x4  __attribute__((ext_vector_type(4)));

__device__ __forceinline__ short bfc(float f) {
  __hip_bfloat16 h = __float2bfloat16(f);
  return __builtin_bit_cast(short, h);
}
__device__ __forceinline__ float b2f(short s) {
  unsigned u = ((unsigned)(unsigned short)s) << 16;
  return __builtin_bit_cast(float, u);
}
__device__ __forceinline__ s16x8 pk8(float4 a, float4 b) {
  s16x8 v;
  v[0]=bfc(a.x); v[1]=bfc(a.y); v[2]=bfc(a.z); v[3]=bfc(a.w);
  v[4]=bfc(b.x); v[5]=bfc(b.y); v[6]=bfc(b.z); v[7]=bfc(b.w);
  return v;
}
__device__ __forceinline__ void gload16(const void* g, void* l) {
  __builtin_amdgcn_global_load_lds((const __attribute__((address_space(1))) void*)g,
                                   (__attribute__((address_space(3))) void*)l, 16, 0, 0);
}

#define DSR128(dst, addr, IMM) \
  asm volatile("ds_read_b128 %0, %1 offset:" IMM : "=v"(dst) : "v"(addr))
#define WAITLGKM(N) do { \
  asm volatile("s_waitcnt lgkmcnt(" #N ")" ::: "memory"); \
  __builtin_amdgcn_sched_barrier(0); } while (0)
#define WAITVM(N) do { \
  asm volatile("s_waitcnt vmcnt(" #N ")" ::: "memory"); \
  __builtin_amdgcn_sched_barrier(0); } while (0)

#define MFMA_BF16 __builtin_amdgcn_mfma_f32_16x16x32_bf16

// ---------------- prep: f32 weights -> bf16 MFMA B-fragment layout ----------------
__global__ __launch_bounds__(256, 4) void prep_kernel(
    const float* __restrict__ src, short* __restrict__ dst,
    int KT, int NP, int Nsrc) {
  __shared__ float tile[32 * 132];
  const int b = blockIdx.x;
  const int np = b % NP;
  const int kt = (b / NP) % KT;
  const int e  = b / (NP * KT);
  const int tid = threadIdx.x;
  const float* s = src + (size_t)e * KT * 32 * (size_t)Nsrc + (size_t)kt * 32 * Nsrc + np * 128;
#pragma unroll
  for (int i = 0; i < 4; i++) {
    const int idx = tid + i * 256;
    const int row = idx >> 5, c4 = idx & 31;
    float4 v = *(const float4*)(s + (size_t)row * Nsrc + c4 * 4);
    *(float4*)(tile + row * 132 + c4 * 4) = v;
  }
  __syncthreads();
  short* dbase = dst + ((size_t)(e * KT + kt) * (NP * 8) + np * 8) * 512;
#pragma unroll
  for (int i = 0; i < 2; i++) {
    const int c = tid + i * 256;
    const int lane = c & 63;
    const int nf = c >> 6;
    const int n = nf * 16 + (lane & 15);
    const int kb = (lane >> 4) * 8;
    s16x8 o;
#pragma unroll
    for (int j = 0; j < 8; j++) o[j] = bfc(tile[(kb + j) * 132 + n]);
    *(s16x8*)(dbase + (size_t)c * 8) = o;
  }
}

// ---------------- router ----------------
__global__ void router_kernel(const float* __restrict__ x, const float* __restrict__ wr,
                              int* __restrict__ cnt, int* __restrict__ lists,
                              float* __restrict__ wlists) {
  const int wave = threadIdx.x >> 6;
  const int lane = threadIdx.x & 63;
  const int t = blockIdx.x * 4 + wave;
  if (t >= NTOK) return;
  float acc[NEXP];
#pragma unroll
  for (int e = 0; e < NEXP; e++) acc[e] = 0.f;
  const float* xrow = x + (size_t)t * HID;
#pragma unroll
  for (int j = 0; j < HID / 256; j++) {
    const int k = j * 256 + lane * 4;
    float4 xv = *(const float4*)(xrow + k);
#pragma unroll
    for (int e = 0; e < NEXP; e++) {
      float4 wv = *(const float4*)(wr + e * HID + k);
      acc[e] += xv.x * wv.x + xv.y * wv.y + xv.z * wv.z + xv.w * wv.w;
    }
  }
#pragma unroll
  for (int e = 0; e < NEXP; e++) {
    float v = acc[e];
    for (int off = 32; off; off >>= 1) v += __shfl_xor(v, off, 64);
    acc[e] = v;
  }
  if (lane == 0) {
    float m = acc[0];
#pragma unroll
    for (int e = 1; e < NEXP; e++) m = fmaxf(m, acc[e]);
    float p[NEXP], s = 0.f;
#pragma unroll
    for (int e = 0; e < NEXP; e++) { p[e] = __expf(acc[e] - m); s += p[e]; }
    const float inv = 1.f / s;
    int e1 = 0; float b1 = p[0];
#pragma unroll
    for (int e = 1; e < NEXP; e++) if (p[e] > b1) { b1 = p[e]; e1 = e; }
    int e2 = -1; float b2 = -1.f;
#pragma unroll
    for (int e = 0; e < NEXP; e++) if (e != e1 && p[e] > b2) { b2 = p[e]; e2 = e; }
    const int pos1 = atomicAdd(&cnt[e1], 1);
    lists[e1 * NTOK + pos1] = t; wlists[e1 * NTOK + pos1] = b1 * inv;
    const int pos2 = atomicAdd(&cnt[e2], 1);
    lists[e2 * NTOK + pos2] = t; wlists[e2 * NTOK + pos2] = b2 * inv;
  }
}

__global__ void offsets_kernel(const int* __restrict__ cnt, int* __restrict__ poffs) {
  if (threadIdx.x == 0 && blockIdx.x == 0) {
    int o = 0;
#pragma unroll
    for (int e = 0; e < NEXP; e++) { poffs[e] = o; o += ((cnt[e] + 255) >> 8) << 8; }
    poffs[NEXP] = o;
  }
}

// ---------------- slotmap ----------------
__global__ void slotmap_kernel(const int* __restrict__ cnt, const int* __restrict__ poffs,
                               const int* __restrict__ lists, const float* __restrict__ wlists,
                               int* __restrict__ slotlist, int* __restrict__ tcnt,
                               int* __restrict__ tok2slot, float* __restrict__ w2) {
  const int e = blockIdx.x;
  const int c = cnt[e], base = poffs[e];
  for (int pos = threadIdx.x; pos < c; pos += blockDim.x) {
    const int tok = lists[e * NTOK + pos];
    const int slot = base + pos;
    slotlist[slot] = tok;
    const int j = atomicAdd(&tcnt[tok], 1);
    tok2slot[tok * 2 + j] = slot;
    w2[tok * 2 + j] = wlists[e * NTOK + pos];
  }
}

// ---------------- gather: x (f32) -> xg bf16 in A-fragment layout ----------------
__global__ __launch_bounds__(256, 4) void gather_kernel(
    const float* __restrict__ x, const int* __restrict__ slotlist,
    short* __restrict__ xg) {
  const int c = blockIdx.x * 256 + threadIdx.x;
  const int cl = c & 63;
  const int fragid = c >> 6;
  const int f = fragid & 15;
  const int kt = (fragid >> 4) & 63;
  const int gmt = fragid >> 10;
  const int tok = slotlist[gmt * 256 + f * 16 + (cl & 15)];
  const float* s = x + (size_t)tok * HID + kt * 32 + (cl >> 4) * 8;
  float4 a = *(const float4*)s, b = *(const float4*)(s + 4);
  *(s16x8*)(xg + (size_t)c * 8) = pk8(a, b);
}

// ---------------- gemm1: 256x128 tile, 8 waves, triple-buffer, counted vmcnt ------
__global__ __launch_bounds__(512, 1) void gemm1_kernel(
    const short* __restrict__ xg, const short* __restrict__ wgb,
    const short* __restrict__ wub, const int* __restrict__ cnt,
    const int* __restrict__ poffs, short* __restrict__ hfrag) {
  const int P = blockIdx.x;
  const int xcd = P & 7, slot = P >> 3;
  const int mt = slot & 31, jj = slot >> 5;
  const int g = jj * 8 + xcd;                 // (e,nt) group pinned to xcd
  const int e = g / NT1, nt = g % NT1;
  if (mt * 256 >= cnt[e]) return;
  const int gmt = (poffs[e] >> 8) + mt;
  const int tid = threadIdx.x;
  const int w = tid >> 6, lane = tid & 63;
  const int wm = w >> 1, wn = w & 1;

  // buffer (16384 shorts = 32KB): A 16 frags [0,8192), Bg [8192,12288), Bu [12288,16384)
  __shared__ __align__(16) short Lds[3 * 16384];
  const uint32_t ldsbase = (uint32_t)(uintptr_t)&Lds[0];

  const short* srcA  = xg  + (size_t)gmt * 64 * 16 * 512 + tid * 8;
  const short* srcBg = wgb + (((size_t)e * 64) * 352 + nt * 8) * 512 + tid * 8;
  const short* srcBu = wub + (((size_t)e * 64) * 352 + nt * 8) * 512 + tid * 8;

  const uint32_t roA = wm * 4096 + lane * 16;
  const uint32_t roB = 16384 + wn * 4096 + lane * 16;
  const uint32_t roU = 24576 + wn * 4096 + lane * 16;

  f32x4 accG[4][4], accU[4][4];
#pragma unroll
  for (int i = 0; i < 4; i++)
#pragma unroll
    for (int j = 0; j < 4; j++) {
      accG[i][j] = f32x4{0.f, 0.f, 0.f, 0.f};
      accU[i][j] = f32x4{0.f, 0.f, 0.f, 0.f};
    }

#define STG1(WB) do {                                                           \
    short* d = (short*)Lds + ((WB) >> 1);                                       \
    gload16(srcA,          d + tid * 8);                                        \
    gload16(srcA + 4096,   d + 4096 + tid * 8);                                 \
    gload16(srcBg,         d + 8192 + tid * 8);                                 \
    gload16(srcBu,         d + 12288 + tid * 8);                                \
    srcA += 8192; srcBg += 180224; srcBu += 180224; } while (0)

#define MMQ(NF)                                                                 \
  { __builtin_amdgcn_s_setprio(1);                                              \
    accG[0][NF] = MFMA_BF16(af[0], bg[NF], accG[0][NF], 0, 0, 0);               \
    accU[0][NF] = MFMA_BF16(af[0], bu[NF], accU[0][NF], 0, 0, 0);               \
    accG[1][NF] = MFMA_BF16(af[1], bg[NF], accG[1][NF], 0, 0, 0);               \
    accU[1][NF] = MFMA_BF16(af[1], bu[NF], accU[1][NF], 0, 0, 0);               \
    accG[2][NF] = MFMA_BF16(af[2], bg[NF], accG[2][NF], 0, 0, 0);               \
    accU[2][NF] = MFMA_BF16(af[2], bu[NF], accU[2][NF], 0, 0, 0);               \
    accG[3][NF] = MFMA_BF16(af[3], bg[NF], accG[3][NF], 0, 0, 0);               \
    accU[3][NF] = MFMA_BF16(af[3], bu[NF], accU[3][NF], 0, 0, 0);               \
    __builtin_amdgcn_s_setprio(0); }

#define G1_BODY(RB, WB, VMN, DOSTG)                                             \
  {                                                                             \
    WAITVM(VMN);                                                                \
    __builtin_amdgcn_s_barrier();                                               \
    const uint32_t rb = ldsbase + (RB);                                         \
    s16x8 af[4], bg[4], bu[4];                                                  \
    DSR128(bg[0], rb + roB, "0");    DSR128(bu[0], rb + roU, "0");              \
    DSR128(af[0], rb + roA, "0");    DSR128(af[1], rb + roA, "1024");           \
    DSR128(af[2], rb + roA, "2048"); DSR128(af[3], rb + roA, "3072");           \
    DSR128(bg[1], rb + roB, "1024"); DSR128(bu[1], rb + roU, "1024");           \
    DSR128(bg[2], rb + roB, "2048"); DSR128(bu[2], rb + roU, "2048");           \
    DSR128(bg[3], rb + roB, "3072"); DSR128(bu[3], rb + roU, "3072");           \
    if (DOSTG) { STG1(WB); }                                                    \
    WAITLGKM(6);                                                                \
    MMQ(0)                                                                      \
    WAITLGKM(4);                                                                \
    MMQ(1)                                                                      \
    WAITLGKM(2);                                                                \
    MMQ(2)                                                                      \
    WAITLGKM(0);                                                                \
    MMQ(3)                                                                      \
  }

  STG1(0);
  STG1(32768);
  for (int it = 0; it < 20; ++it) {          // t = 0..59
    G1_BODY(0,     65536, 4, 1)
    G1_BODY(32768, 0,     4, 1)
    G1_BODY(65536, 32768, 4, 1)
  }
  G1_BODY(0,     65536, 4, 1)                // t=60, stg 62 -> buf2
  G1_BODY(32768, 0,     4, 1)                // t=61, stg 63 -> buf0
  G1_BODY(65536, 0,     4, 0)                // t=62
  G1_BODY(0,     0,     0, 0)                // t=63
#undef G1_BODY
#undef MMQ
#undef STG1

  // epilogue: silu-gate, LDS transpose 256x128 (pad 136), store gemm2 A-frag layout
  short* tr = (short*)Lds;                   // 256*136*2B = 69632 <= 98304
  __syncthreads();
#pragma unroll
  for (int mf = 0; mf < 4; mf++)
#pragma unroll
    for (int reg = 0; reg < 4; reg++) {
      const int row = wm * 64 + mf * 16 + (lane >> 4) * 4 + reg;
#pragma unroll
      for (int nf = 0; nf < 4; nf++) {
        const int col = wn * 64 + nf * 16 + (lane & 15);
        const float gv = accG[mf][nf][reg];
        const float uv = accU[mf][nf][reg];
        tr[row * 136 + col] = bfc((gv / (1.f + __expf(-gv))) * uv);
      }
    }
  __syncthreads();
  short* hb = hfrag + (((size_t)gmt * 176 + nt * 4) * 16) * 512;
#pragma unroll
  for (int i = 0; i < 8; i++) {
    const int c = tid + i * 512;             // 0..4095
    const int cl = c & 63;
    const int f = (c >> 6) & 15;
    const int ktl = c >> 10;                 // 0..3
    const int rr = f * 16 + (cl & 15);
    s16x8 v = *(const s16x8*)(tr + rr * 136 + ktl * 32 + (cl >> 4) * 8);
    *(s16x8*)(hb + ((size_t)ktl * 16 + f) * 512 + cl * 8) = v;
  }
}

// ---------------- gemm2: 256x128 tile, 8 waves, triple-buffer, counted vmcnt ------
__global__ __launch_bounds__(512, 4) void gemm2_kernel(
    const short* __restrict__ hfrag, const short* __restrict__ wdb,
    const int* __restrict__ cnt, const int* __restrict__ poffs,
    __hip_bfloat16* __restrict__ pout) {
  const int P = blockIdx.x;
  const int xcd = P & 7, r = P >> 3;
  const int nt = r & 15, emq = r >> 4;
  const int gm = emq * 8 + xcd;              // m-tile pinned to xcd
  const int e = gm >> 5, mt = gm & 31;
  if (mt * 256 >= cnt[e]) return;
  const int gmt = (poffs[e] >> 8) + mt;
  const int n0 = nt * 128;
  const int tid = threadIdx.x;
  const int w = tid >> 6, lane = tid & 63;
  const int wm = w >> 1, wn = w & 1;

  // buffer (12288 shorts = 24KB): A 16 frags [0,8192), B 8 frags [8192,12288)
  __shared__ __align__(16) short Lds[3 * 12288];
  const uint32_t ldsbase = (uint32_t)(uintptr_t)&Lds[0];

  const short* srcA = hfrag + (size_t)gmt * 176 * 16 * 512 + tid * 8;
  const short* srcB = wdb + (((size_t)e * 176) * 128 + nt * 8) * 512 + tid * 8;

  const uint32_t roA = wm * 4096 + lane * 16;
  const uint32_t roB = 16384 + wn * 4096 + lane * 16;

  f32x4 acc[4][4];
#pragma unroll
  for (int i = 0; i < 4; i++)
#pragma unroll
    for (int j = 0; j < 4; j++) acc[i][j] = f32x4{0.f, 0.f, 0.f, 0.f};

#define STG2(WB) do {                                                           \
    short* d = (short*)Lds + ((WB) >> 1);                                       \
    gload16(srcA,        d + w * 512);                                          \
    gload16(srcA + 4096, d + 4096 + w * 512);                                   \
    gload16(srcB,        d + 8192 + w * 512);                                   \
    srcA += 8192; srcB += 65536; } while (0)

#define MMQ2(NF, BF)                                                            \
  { __builtin_amdgcn_s_setprio(1);                                              \
    acc[0][NF] = MFMA_BF16(af0, BF, acc[0][NF], 0, 0, 0);                       \
    acc[1][NF] = MFMA_BF16(af1, BF, acc[1][NF], 0, 0, 0);                       \
    acc[2][NF] = MFMA_BF16(af2, BF, acc[2][NF], 0, 0, 0);                       \
    acc[3][NF] = MFMA_BF16(af3, BF, acc[3][NF], 0, 0, 0);                       \
    __builtin_amdgcn_s_setprio(0); }

#define G2_BODY(RB, WB, VMN, DOSTG)                                             \
  {                                                                             \
    WAITVM(VMN);                                                                \
    __builtin_amdgcn_s_barrier();                                               \
    const uint32_t rb = ldsbase + (RB);                                         \
    s16x8 af0, af1, af2, af3, bf0, bf1, bf2, bf3;                               \
    DSR128(bf0, rb + roB, "0");                                                 \
    DSR128(af0, rb + roA, "0");    DSR128(af1, rb + roA, "1024");               \
    DSR128(af2, rb + roA, "2048"); DSR128(af3, rb + roA, "3072");               \
    DSR128(bf1, rb + roB, "1024");                                              \
    DSR128(bf2, rb + roB, "2048");                                              \
    DSR128(bf3, rb + roB, "3072");                                              \
    if (DOSTG) { STG2(WB); }                                                    \
    WAITLGKM(3);                                                                \
    MMQ2(0, bf0)                                                                \
    WAITLGKM(2);                                                                \
    MMQ2(1, bf1)                                                                \
    WAITLGKM(1);                                                                \
    MMQ2(2, bf2)                                                                \
    WAITLGKM(0);                                                                \
    MMQ2(3, bf3)                                                                \
  }

  STG2(0);
  STG2(24576);
  for (int it = 0; it < 58; ++it) {          // t = 0..173
    G2_BODY(0,     49152, 3, 1)
    G2_BODY(24576, 0,     3, 1)
    G2_BODY(49152, 24576, 3, 1)
  }
  G2_BODY(0,     0, 3, 0)                    // t=174
  G2_BODY(24576, 0, 0, 0)                    // t=175
#undef G2_BODY
#undef MMQ2
#undef STG2

  const int slotb = poffs[e] + mt * 256;
#pragma unroll
  for (int mf = 0; mf < 4; mf++) {
#pragma unroll
    for (int reg = 0; reg < 4; reg++) {
      const int row = wm * 64 + mf * 16 + (lane >> 4) * 4 + reg;
      __hip_bfloat16* op = pout + (size_t)(slotb + row) * HID + n0 + wn * 64 + (lane & 15);
#pragma unroll
      for (int nf = 0; nf < 4; nf++)
        op[nf * 16] = __float2bfloat16(acc[mf][nf][reg]);
    }
  }
}

// ---------------- combine ----------------
__global__ __launch_bounds__(256, 8) void combine_kernel(
    const __hip_bfloat16* __restrict__ pout, const int* __restrict__ tok2slot,
    const float* __restrict__ w2, float* __restrict__ out) {
  const int t = blockIdx.x;
  const int s0 = tok2slot[2 * t], s1 = tok2slot[2 * t + 1];
  const float w0 = w2[2 * t], w1 = w2[2 * t + 1];
  const short* p0 = (const short*)pout + (size_t)s0 * HID;
  const short* p1 = (const short*)pout + (size_t)s1 * HID;
  float* o = out + (size_t)t * HID;
  const int i = threadIdx.x;
  s16x8 a = *(const s16x8*)(p0 + i * 8);
  s16x8 b = *(const s16x8*)(p1 + i * 8);
  float4 r0, r1;
  r0.x = w0 * b2f(a[0]) + w1 * b2f(b[0]);
  r0.y = w0 * b2f(a[1]) + w1 * b2f(b[1]);
  r0.z = w0 * b2f(a[2]) + w1 * b2f(b[2]);
  r0.w = w0 * b2f(a[3]) + w1 * b2f(b[3]);
  r1.x = w0 * b2f(a[4]) + w1 * b2f(b[4]);
  r1.y = w0 * b2f(a[5]) + w1 * b2f(b[5]);
  r1.z = w0 * b2f(a[6]) + w1 * b2f(b[6]);
  r1.w = w0 * b2f(a[7]) + w1 * b2f(b[7]);
  *(float4*)(o + i * 8) = r0;
  *(float4*)(o + i * 8 + 4) = r1;
}

extern "C" void kernel_launch(void* const* d_in, const int* in_sizes, int n_in,
                              void* d_out, int out_size, void* d_ws, size_t ws_size,
                              hipStream_t stream) {
  const float* x  = (const float*)d_in[0];
  const float* wr = (const float*)d_in[1];
  const float* wg = (const float*)d_in[2];
  const float* wu = (const float*)d_in[3];
  const float* wd = (const float*)d_in[4];
  float* out = (float*)d_out;
  char* ws = (char*)d_ws;

  int* cnt      = (int*)ws;
  int* poffs    = (int*)(ws + 64);
  int* tcnt     = (int*)(ws + TCNT_OFF);
  int* slotlist = (int*)(ws + SLOT_OFF);
  int* tok2slot = (int*)(ws + T2S_OFF);
  float* w2     = (float*)(ws + W2_OFF);
  int* lists    = (int*)(ws + LISTS_OFF);
  float* wlists = (float*)(ws + WL_OFF);
  short* wgb    = (short*)(ws + WG_OFF);
  short* wub    = (short*)(ws + WU_OFF);
  short* wdb    = (short*)(ws + WG_OFF);     // reuses wgb region (after gemm1)
  short* hfrag  = (short*)(ws + HF_OFF);
  short* xg     = (short*)(ws + XG_OFF);
  __hip_bfloat16* pout = (__hip_bfloat16*)(ws + XG_OFF);  // reuses xg (after gemm1)

  (void)hipMemsetAsync(ws, 0, 256, stream);
  (void)hipMemsetAsync(ws + TCNT_OFF, 0, 32768, stream);
  (void)hipMemsetAsync(ws + SLOT_OFF, 0, 73728, stream);

  router_kernel<<<NTOK / 4, 256, 0, stream>>>(x, wr, cnt, lists, wlists);
  offsets_kernel<<<1, 64, 0, stream>>>(cnt, poffs);
  slotmap_kernel<<<NEXP, 256, 0, stream>>>(cnt, poffs, lists, wlists, slotlist, tcnt, tok2slot, w2);
  gather_kernel<<<18432, 256, 0, stream>>>(x, slotlist, xg);
  prep_kernel<<<NEXP * 64 * 44, 256, 0, stream>>>(wg, wgb, 64, 44, INTR);
  prep_kernel<<<NEXP * 64 * 44, 256, 0, stream>>>(wu, wub, 64, 44, INTR);
  gemm1_kernel<<<8 * 32 * NT1, 512, 0, stream>>>(xg, wgb, wub, cnt, poffs, hfrag);
  prep_kernel<<<NEXP * 176 * 16, 256, 0, stream>>>(wd, wdb, 176, 16, HID);
  gemm2_kernel<<<8 * 16 * 32, 512, 0, stream>>>(hfrag, wdb, cnt, poffs, pout);
  combine_kernel<<<NTOK, 256, 0, stream>>>(pout, tok2slot, w2, out);
}